// Round 9
// baseline (219.022 us; speedup 1.0000x reference)
//
#include <hip/hip_runtime.h>
#include <stdint.h>

typedef unsigned short ushort_t;
typedef __attribute__((ext_vector_type(8))) __bf16 bf16x8;
typedef __attribute__((ext_vector_type(4))) float floatx4;
typedef __attribute__((ext_vector_type(2))) uint32_t uint32x2;

__device__ __forceinline__ ushort_t f2bf(float f) {
    uint32_t u = __builtin_bit_cast(uint32_t, f);
    u += 0x7fffu + ((u >> 16) & 1u);
    return (ushort_t)(u >> 16);
}

// async 16B global->LDS (deposit at ldsbase + lane*16; ldsbase wave-uniform)
typedef __attribute__((address_space(1))) const void glb_void;
typedef __attribute__((address_space(3))) void lds_void;
__device__ __forceinline__ void gld16(const void* g, void* l) {
    __builtin_amdgcn_global_load_lds((glb_void*)g, (lds_void*)l, 16, 0, 0);
}

// Q pre-scale: dh^-0.5 * log2(e) so attention softmax runs in exp2 domain.
#define QSCALE 0.18033688011112042f

// ---------------- cast: fp32 -> bf16 ----------------
__global__ void cast_kernel(const float* __restrict__ x,
                            const float* __restrict__ Wq, const float* __restrict__ Wk,
                            const float* __restrict__ Wv, const float* __restrict__ Wp,
                            ushort_t* __restrict__ xb, ushort_t* __restrict__ Wqkvb,
                            ushort_t* __restrict__ Wpb)
{
    const int64_t NX = 4194304, NW = 1048576;
    int64_t i4 = ((int64_t)blockIdx.x * blockDim.x + threadIdx.x) * 4;
    const float* src; ushort_t* dst; int64_t off;
    if (i4 < NX)            { src = x;  dst = xb;          off = i4; }
    else if (i4 < NX+NW)    { src = Wq; dst = Wqkvb;       off = i4 - NX; }
    else if (i4 < NX+2*NW)  { src = Wk; dst = Wqkvb + NW;  off = i4 - NX - NW; }
    else if (i4 < NX+3*NW)  { src = Wv; dst = Wqkvb + 2*NW;off = i4 - NX - 2*NW; }
    else                    { src = Wp; dst = Wpb;         off = i4 - NX - 3*NW; }
    float4 v = *(const float4*)(src + off);
    ushort4 o;
    o.x = f2bf(v.x); o.y = f2bf(v.y); o.z = f2bf(v.z); o.w = f2bf(v.w);
    *(ushort4*)(dst + off) = o;
}

// ---------------- bf16 GEMM: D = A @ B^T  (global_load_lds staging) ----------------
// mode 0: scatter Q,K -> [bh][s][d] (Q pre-scaled), V -> TRANSPOSED [bh][d][s]
// mode 1: fp32 out = D + bias
#define BM 128
#define BN 128
#define BK 32

__global__ __launch_bounds__(256, 3)
void gemm_bt(const ushort_t* __restrict__ A, const ushort_t* __restrict__ Bmat,
             int M, int N, int K, int mode,
             ushort_t* __restrict__ qb, ushort_t* __restrict__ kb, ushort_t* __restrict__ vtb,
             float* __restrict__ outf, const float* __restrict__ bias)
{
    __shared__ ushort_t As[BM * BK];   // 8KB, row-major, unpadded (lane-linear deposits)
    __shared__ ushort_t Bs[BN * BK];   // 8KB
    const int tid  = threadIdx.x;
    const int lane = tid & 63;
    const int wave = tid >> 6;
    const int m0 = blockIdx.x * BM;
    const int n0 = blockIdx.y * BN;
    const int wrow = (wave >> 1) * 64;
    const int wcol = (wave & 1) * 64;
    const int q_ = lane >> 4;
    const int ml = lane & 15;

    floatx4 acc[4][4];
    for (int i = 0; i < 4; i++) for (int j = 0; j < 4; j++) acc[i][j] = floatx4{0.f,0.f,0.f,0.f};

    // staging: 8 blocks of 1KB per tile (16 rows x 32 cols); wave w does blocks 2w,2w+1
    const int t0 = wave * 2, t1 = wave * 2 + 1;
    const int row_l = lane >> 2;         // 0..15
    const int col_l = (lane & 3) * 8;    // 0,8,16,24
    const ushort_t* Ag0 = A    + (int64_t)(m0 + t0*16 + row_l) * K + col_l;
    const ushort_t* Ag1 = A    + (int64_t)(m0 + t1*16 + row_l) * K + col_l;
    const ushort_t* Bg0 = Bmat + (int64_t)(n0 + t0*16 + row_l) * K + col_l;
    const ushort_t* Bg1 = Bmat + (int64_t)(n0 + t1*16 + row_l) * K + col_l;
    ushort_t* Al0 = As + t0*512; ushort_t* Al1 = As + t1*512;
    ushort_t* Bl0 = Bs + t0*512; ushort_t* Bl1 = Bs + t1*512;

    for (int k0 = 0; k0 < K; k0 += BK) {
        __syncthreads();
        gld16(Ag0 + k0, Al0);
        gld16(Ag1 + k0, Al1);
        gld16(Bg0 + k0, Bl0);
        gld16(Bg1 + k0, Bl1);
        __syncthreads();
        bf16x8 af[4], bf[4];
        for (int mt = 0; mt < 4; mt++)
            af[mt] = *(const bf16x8*)(As + (wrow + mt*16 + ml) * BK + q_*8);
        for (int nt = 0; nt < 4; nt++)
            bf[nt] = *(const bf16x8*)(Bs + (wcol + nt*16 + ml) * BK + q_*8);
        for (int mt = 0; mt < 4; mt++)
            for (int nt = 0; nt < 4; nt++)
                acc[mt][nt] = __builtin_amdgcn_mfma_f32_16x16x32_bf16(af[mt], bf[nt], acc[mt][nt], 0, 0, 0);
    }

    if (mode == 0) {
        for (int mt = 0; mt < 4; mt++) for (int nt = 0; nt < 4; nt++) {
            floatx4 v = acc[mt][nt];
            int col = n0 + wcol + nt*16 + ml;
            int which = col >> 10;
            int nn = col & 1023;
            int h = nn >> 6, d = nn & 63;
            if (which < 2) {
                ushort_t* dst = (which == 0) ? qb : kb;
                float sc = (which == 0) ? QSCALE : 1.0f;
                for (int r = 0; r < 4; r++) {
                    int rowg = m0 + wrow + mt*16 + q_*4 + r;
                    int b = rowg >> 11, s = rowg & 2047;
                    dst[(((int64_t)(b*16 + h) * 2048 + s) << 6) + d] = f2bf(v[r] * sc);
                }
            } else {
                int rowg0 = m0 + wrow + mt*16 + q_*4;
                int b = rowg0 >> 11, sbase = rowg0 & 2047;
                ushort4 o;
                o.x = f2bf(v[0]); o.y = f2bf(v[1]); o.z = f2bf(v[2]); o.w = f2bf(v[3]);
                *(ushort4*)(vtb + (((int64_t)(b*16 + h) * 64 + d) << 11) + sbase) = o;
            }
        }
    } else {
        for (int mt = 0; mt < 4; mt++) for (int nt = 0; nt < 4; nt++) {
            floatx4 v = acc[mt][nt];
            int col = n0 + wcol + nt*16 + ml;
            float bv = bias[col];
            for (int r = 0; r < 4; r++) {
                int rowg = m0 + wrow + mt*16 + q_*4 + r;
                outf[(int64_t)rowg * N + col] = v[r] + bv;
            }
        }
    }
}

// -------- fused masked flash attention: wave-autonomous key-split, 64 q/block --------
// Each wave computes ALL 64 q-rows against ITS 32 keys of the 128-key chunk.
// Wave w reads only the K blocks (ids 4w..4w+3) and V blocks (ids 4w..4w+3) it
// staged itself -> ZERO barriers in the chunk loop; per-wave async staging with
// counted vmcnt(4) (K(t+1) issued after K-frags in regs, V(t+1) after V-frags in
// regs). LDS reads/wave-chunk: 12 b128 + 8 b64 (3x fewer than r8). O and lsum are
// per-wave partials over keys; one cross-wave LDS reduction at the end (48KB
// overlay on K/V/P, 2 barriers total). Swapped QK^T datapath as verified r3-r8.
__global__ __launch_bounds__(256, 3)
void attn_kernel(const ushort_t* __restrict__ Q, const ushort_t* __restrict__ Kb,
                 const ushort_t* __restrict__ Vt, ushort_t* __restrict__ Out)
{
    __shared__ ushort_t LDS[26624];      // 53248B: K 16KB | V 16KB | P 4x5KB
    ushort_t* Kl = LDS;                  // 16 blocks of 512 shorts
    ushort_t* Vl = LDS + 8192;
    // per-wave P: [64 q][stride 40 shorts] (2-way bank alias = free)

    int bi = blockIdx.x;                 // 1024 blocks
    int bh = (bi & 7) + 8 * ((bi >> 3) & 3);   // low 3 bits -> XCD spread
    int qt4 = (bi >> 5) & 3;             // 64-row q piece
    int qv = 7 - (bi >> 7);              // heavy views first
    int b = bh >> 4, h = bh & 15;
    int tid = threadIdx.x;
    int wave = tid >> 6, lane = tid & 63;
    int q_ = lane >> 4, ml = lane & 15;
    int rlane = lane & 15, clane = lane >> 4;
    int sB = qv*256 + qt4*64;            // block's 64 q-rows

    const ushort_t* Kbh = Kb + ((int64_t)bh << 17);
    const ushort_t* Vbh = Vt + ((int64_t)bh << 17);
    ushort_t* Pw = LDS + 16384 + wave * 2560;

    // Q fragments for all 4 q-tiles (B-operand rows = q)
    bf16x8 aq0[4], aq1[4];
    #pragma unroll
    for (int qt = 0; qt < 4; qt++) {
        const ushort_t* Qp = Q + (((int64_t)bh*2048 + sB + qt*16 + ml) << 6) + q_*8;
        aq0[qt] = *(const bf16x8*)(Qp);
        aq1[qt] = *(const bf16x8*)(Qp + 32);
    }

    floatx4 o_acc[4][4];                 // [qt][dt] partial over this wave's keys
    #pragma unroll
    for (int i = 0; i < 4; i++)
        #pragma unroll
        for (int j = 0; j < 4; j++) o_acc[i][j] = floatx4{0.f,0.f,0.f,0.f};
    float lsum[4] = {0.f, 0.f, 0.f, 0.f};

    const int nviews = (qv < 2) ? 1 : (qv + 1);
    const int NT = nviews * 2;
    const int vfix = qv ^ 1;             // the single view when nviews==1

    // wave-private staging (ids wave*4..wave*4+3 for both K and V):
    // K id: keys (id>>1)*16 + rlane, d (id&1)*32 + clane*8  -> Kl + id*512
    // V id: d (id&3)*16 + rlane, keys (id>>2)*32 + clane*8  -> Vl + id*512
    // wave reads exactly its own blocks: K tiles kt=2w,2w+1; V keys 32w..32w+31.

    // ---- prologue: issue K(0) then V(0) (order matters for vmcnt) ----
    {
        int koff = ((nviews == 1) ? vfix : 0) * 256;
        #pragma unroll
        for (int i = 0; i < 4; i++) {
            int id = wave*4 + i;
            const ushort_t* gk = Kbh + (((int64_t)(koff + (id >> 1)*16 + rlane)) << 6)
                                     + (id & 1)*32 + clane*8;
            gld16(gk, Kl + id*512);
        }
        #pragma unroll
        for (int i = 0; i < 4; i++) {
            int id = wave*4 + i;
            const ushort_t* gv = Vbh + ((int64_t)((id & 3)*16 + rlane) << 11)
                                     + koff + (id >> 2)*32 + clane*8;
            gld16(gv, Vl + id*512);
        }
    }

    for (int t = 0; t < NT; ++t) {
        // outstanding here: K(t) 4 (oldest) + V(t) 4 -> wait K(t)
        asm volatile("s_waitcnt vmcnt(4)" ::: "memory");

        // ---- K fragments -> regs (own blocks only) ----
        bf16x8 kf[4];
        kf[0] = *(const bf16x8*)(Kl + (2*wave    )*1024       + lane*8);
        kf[1] = *(const bf16x8*)(Kl + (2*wave    )*1024 + 512 + lane*8);
        kf[2] = *(const bf16x8*)(Kl + (2*wave + 1)*1024       + lane*8);
        kf[3] = *(const bf16x8*)(Kl + (2*wave + 1)*1024 + 512 + lane*8);
        asm volatile("s_waitcnt lgkmcnt(0)" ::: "memory");  // K buffer drained

        if (t + 1 < NT) {               // issue K(t+1) into the freed K region
            int koff_n = ((nviews == 1) ? vfix : ((t + 1) >> 1)) * 256 + ((t + 1) & 1) * 128;
            #pragma unroll
            for (int i = 0; i < 4; i++) {
                int id = wave*4 + i;
                const ushort_t* gk = Kbh + (((int64_t)(koff_n + (id >> 1)*16 + rlane)) << 6)
                                         + (id & 1)*32 + clane*8;
                gld16(gk, Kl + id*512);
            }
        }

        // ---- S = K @ Q^T for all 4 q-tiles over this wave's 32 keys ----
        // lane holds P[q = qt*16+ml][key = 16*(2w+ktl) + 4*q_ + r]
        #pragma unroll
        for (int ktl = 0; ktl < 2; ktl++) {
            #pragma unroll
            for (int qt = 0; qt < 4; qt++) {
                floatx4 cz = floatx4{0.f,0.f,0.f,0.f};
                cz = __builtin_amdgcn_mfma_f32_16x16x32_bf16(kf[ktl*2    ], aq0[qt], cz, 0, 0, 0);
                cz = __builtin_amdgcn_mfma_f32_16x16x32_bf16(kf[ktl*2 + 1], aq1[qt], cz, 0, 0, 0);
                float p0 = __builtin_amdgcn_exp2f(cz[0]);
                float p1 = __builtin_amdgcn_exp2f(cz[1]);
                float p2 = __builtin_amdgcn_exp2f(cz[2]);
                float p3 = __builtin_amdgcn_exp2f(cz[3]);
                lsum[qt] += (p0 + p1) + (p2 + p3);
                uint32x2 wv;
                wv[0] = (uint32_t)f2bf(p0) | ((uint32_t)f2bf(p1) << 16);
                wv[1] = (uint32_t)f2bf(p2) | ((uint32_t)f2bf(p3) << 16);
                // P[q][local key]: row qt*16+ml, keys ktl*16 + q_*4..+3
                *(uint32x2*)(Pw + (qt*16 + ml)*40 + ktl*16 + q_*4) = wv;
            }
        }
        asm volatile("s_waitcnt lgkmcnt(0)" ::: "memory");  // wave-private P visible

        // ---- P A-frags (row=q, k = local key q_*8+j) ----
        bf16x8 ap[4];
        #pragma unroll
        for (int qt = 0; qt < 4; qt++)
            ap[qt] = *(const bf16x8*)(Pw + (qt*16 + ml)*40 + q_*8);

        // ---- V(t) ready? outstanding: K(t+1) 4 if issued ----
        if (t + 1 < NT) asm volatile("s_waitcnt vmcnt(4)" ::: "memory");
        else            asm volatile("s_waitcnt vmcnt(0)" ::: "memory");

        bf16x8 vv[4];
        #pragma unroll
        for (int dt = 0; dt < 4; dt++)
            vv[dt] = *(const bf16x8*)(Vl + (wave*4 + dt)*512 + lane*8);
        asm volatile("s_waitcnt lgkmcnt(0)" ::: "memory");  // V buffer drained

        if (t + 1 < NT) {               // issue V(t+1) into the freed V region
            int koff_n = ((nviews == 1) ? vfix : ((t + 1) >> 1)) * 256 + ((t + 1) & 1) * 128;
            #pragma unroll
            for (int i = 0; i < 4; i++) {
                int id = wave*4 + i;
                const ushort_t* gv = Vbh + ((int64_t)((id & 3)*16 + rlane) << 11)
                                         + koff_n + (id >> 2)*32 + clane*8;
                gld16(gv, Vl + id*512);
            }
        }

        // ---- O[qt] += P[qt] @ V (K=32 over this wave's keys) ----
        #pragma unroll
        for (int qt = 0; qt < 4; qt++)
            #pragma unroll
            for (int dt = 0; dt < 4; dt++)
                o_acc[qt][dt] = __builtin_amdgcn_mfma_f32_16x16x32_bf16(ap[qt], vv[dt], o_acc[qt][dt], 0, 0, 0);
    }

    // ---- in-wave l reduction: sum across q_ quarters (row = ml per qt) ----
    #pragma unroll
    for (int qt = 0; qt < 4; qt++) {
        lsum[qt] += __shfl_xor(lsum[qt], 16);
        lsum[qt] += __shfl_xor(lsum[qt], 32);
    }

    // ---- cross-wave reduction via LDS overlay (K/V/P regions dead now) ----
    floatx4* red4 = (floatx4*)LDS;               // 12 regions x 256 floatx4 = 48KB
    float*   redl = (float*)LDS + 12288;         // 12 x 16 floats
    __syncthreads();                             // all waves done with K/V/P
    #pragma unroll
    for (int qt = 0; qt < 4; qt++) {
        if (qt == wave) continue;
        int widx = wave - (wave > qt ? 1 : 0);   // 0..2
        #pragma unroll
        for (int dt = 0; dt < 4; dt++)
            red4[(qt*3 + widx)*256 + (dt*16 + ml)*4 + q_] = o_acc[qt][dt];
        if (q_ == 0) redl[(qt*3 + widx)*16 + ml] = lsum[qt];
    }
    __syncthreads();
    #pragma unroll
    for (int qt = 0; qt < 4; qt++) {
        if (qt != wave) continue;
        #pragma unroll
        for (int j = 0; j < 3; j++) {
            #pragma unroll
            for (int dt = 0; dt < 4; dt++)
                o_acc[qt][dt] += red4[(qt*3 + j)*256 + (dt*16 + ml)*4 + q_];
            lsum[qt] += redl[(qt*3 + j)*16 + ml];
        }
    }

    // ---- epilogue: wave w writes q-tile qt == w ----
    #pragma unroll
    for (int qt = 0; qt < 4; qt++) {
        if (qt != wave) continue;
        float rinv[4];
        #pragma unroll
        for (int r = 0; r < 4; r++)
            rinv[r] = 1.0f / __shfl(lsum[qt], q_*4 + r);   // row q_*4+r's l at lane ml=q_*4+r
        #pragma unroll
        for (int dt = 0; dt < 4; dt++)
            #pragma unroll
            for (int r = 0; r < 4; r++) {
                int sr = sB + qt*16 + q_*4 + r;
                Out[((int64_t)b*2048 + sr) * 1024 + h*64 + dt*16 + ml] =
                    f2bf(o_acc[qt][dt][r] * rinv[r]);
            }
    }
}

extern "C" void kernel_launch(void* const* d_in, const int* in_sizes, int n_in,
                              void* d_out, int out_size, void* d_ws, size_t ws_size,
                              hipStream_t stream) {
    const float* x  = (const float*)d_in[0];
    const float* Wq = (const float*)d_in[1];
    const float* Wk = (const float*)d_in[2];
    const float* Wv = (const float*)d_in[3];
    const float* Wp = (const float*)d_in[4];
    const float* bp = (const float*)d_in[5];
    float* out = (float*)d_out;

    char* ws = (char*)d_ws;
    ushort_t* xb    = (ushort_t*)(ws);
    ushort_t* Wqkvb = (ushort_t*)(ws + ((size_t)8  << 20));
    ushort_t* Wpb   = (ushort_t*)(ws + ((size_t)14 << 20));
    ushort_t* qb    = (ushort_t*)(ws + ((size_t)16 << 20));
    ushort_t* kbuf  = (ushort_t*)(ws + ((size_t)24 << 20));
    ushort_t* vtb   = (ushort_t*)(ws + ((size_t)40 << 20));
    ushort_t* attno = xb;

    cast_kernel<<<8192, 256, 0, stream>>>(x, Wq, Wk, Wv, Wp, xb, Wqkvb, Wpb);

    dim3 g0(4096 / BM, 3072 / BN);
    gemm_bt<<<g0, 256, 0, stream>>>(xb, Wqkvb, 4096, 3072, 1024, 0,
                                    qb, kbuf, vtb, nullptr, nullptr);

    attn_kernel<<<1024, 256, 0, stream>>>(qb, kbuf, vtb, attno);

    dim3 g1(4096 / BM, 1024 / BN);
    gemm_bt<<<g1, 256, 0, stream>>>(attno, Wpb, 4096, 1024, 1024, 1,
                                    nullptr, nullptr, nullptr, out, bp);
}

// Round 10
// 173.341 us; speedup vs baseline: 1.2635x; 1.2635x over previous
//
#include <hip/hip_runtime.h>
#include <stdint.h>

typedef unsigned short ushort_t;
typedef __attribute__((ext_vector_type(8))) __bf16 bf16x8;
typedef __attribute__((ext_vector_type(4))) float floatx4;
typedef __attribute__((ext_vector_type(2))) uint32_t uint32x2;

__device__ __forceinline__ ushort_t f2bf(float f) {
    uint32_t u = __builtin_bit_cast(uint32_t, f);
    u += 0x7fffu + ((u >> 16) & 1u);
    return (ushort_t)(u >> 16);
}

// async 16B global->LDS (deposit at ldsbase + lane*16; ldsbase wave-uniform)
typedef __attribute__((address_space(1))) const void glb_void;
typedef __attribute__((address_space(3))) void lds_void;
__device__ __forceinline__ void gld16(const void* g, void* l) {
    __builtin_amdgcn_global_load_lds((glb_void*)g, (lds_void*)l, 16, 0, 0);
}

// Q pre-scale: dh^-0.5 * log2(e) so attention softmax runs in exp2 domain.
#define QSCALE 0.18033688011112042f

// ---------------- cast: fp32 -> bf16 ----------------
__global__ void cast_kernel(const float* __restrict__ x,
                            const float* __restrict__ Wq, const float* __restrict__ Wk,
                            const float* __restrict__ Wv, const float* __restrict__ Wp,
                            ushort_t* __restrict__ xb, ushort_t* __restrict__ Wqkvb,
                            ushort_t* __restrict__ Wpb)
{
    const int64_t NX = 4194304, NW = 1048576;
    int64_t i4 = ((int64_t)blockIdx.x * blockDim.x + threadIdx.x) * 4;
    const float* src; ushort_t* dst; int64_t off;
    if (i4 < NX)            { src = x;  dst = xb;          off = i4; }
    else if (i4 < NX+NW)    { src = Wq; dst = Wqkvb;       off = i4 - NX; }
    else if (i4 < NX+2*NW)  { src = Wk; dst = Wqkvb + NW;  off = i4 - NX - NW; }
    else if (i4 < NX+3*NW)  { src = Wv; dst = Wqkvb + 2*NW;off = i4 - NX - 2*NW; }
    else                    { src = Wp; dst = Wpb;         off = i4 - NX - 3*NW; }
    float4 v = *(const float4*)(src + off);
    ushort4 o;
    o.x = f2bf(v.x); o.y = f2bf(v.y); o.z = f2bf(v.z); o.w = f2bf(v.w);
    *(ushort4*)(dst + off) = o;
}

// ---------------- bf16 GEMM: D = A @ B^T  (global_load_lds staging) ----------------
// Templated tile: BM x BN, K-step BK (BK=64 halves barrier count vs the verified
// BK=32 structure; all fragment/staging math is the verified map scaled).
// MODE 0: scatter Q,K -> [bh][s][d] (Q pre-scaled), V -> TRANSPOSED [bh][d][s]
// MODE 1: fp32 out = D + bias
template<int BM, int BN, int BK, int MODE>
__global__ __launch_bounds__(256, 3)
void gemm_bt(const ushort_t* __restrict__ A, const ushort_t* __restrict__ Bmat,
             int M, int N, int K,
             ushort_t* __restrict__ qb, ushort_t* __restrict__ kb, ushort_t* __restrict__ vtb,
             float* __restrict__ outf, const float* __restrict__ bias)
{
    constexpr int KB32 = BK / 32;                 // 32-col halves per K-step
    constexpr int NA = (BM / 16) * KB32;          // A staging blocks (1KB each)
    constexpr int NB = (BN / 16) * KB32;
    constexpr int NS = (NA + NB) / 4;             // staging blocks per wave
    constexpr int MT = BM / 32;                   // acc m-tiles per wave
    constexpr int NTW = BN / 32;                  // acc n-tiles per wave
    __shared__ ushort_t As[BM * BK];
    __shared__ ushort_t Bs[BN * BK];
    const int tid  = threadIdx.x;
    const int lane = tid & 63;
    const int wave = tid >> 6;
    const int m0 = blockIdx.x * BM;
    const int n0 = blockIdx.y * BN;
    const int wrow = (wave >> 1) * (BM / 2);
    const int wcol = (wave & 1) * (BN / 2);
    const int q_ = lane >> 4;
    const int ml = lane & 15;
    (void)M;

    floatx4 acc[MT][NTW];
    #pragma unroll
    for (int i = 0; i < MT; i++)
        #pragma unroll
        for (int j = 0; j < NTW; j++) acc[i][j] = floatx4{0.f,0.f,0.f,0.f};

    // staging blocks: id < NA -> A block (rows rg*16.., cols ch*32..), else B.
    // deposit lane-linear: LDS blk*512 + row_l*32 + col_l == base + lane*8 shorts.
    const int row_l = lane >> 2;         // 0..15
    const int col_l = (lane & 3) * 8;    // 0,8,16,24
    const ushort_t* gptr[NS];
    ushort_t* lptr[NS];
    #pragma unroll
    for (int i = 0; i < NS; i++) {
        int id = wave * NS + i;
        if (id < NA) {
            int rg = id / KB32, ch = id % KB32;
            gptr[i] = A + (int64_t)(m0 + rg*16 + row_l) * K + ch*32 + col_l;
            lptr[i] = As + id * 512;
        } else {
            int id2 = id - NA;
            int rg = id2 / KB32, ch = id2 % KB32;
            gptr[i] = Bmat + (int64_t)(n0 + rg*16 + row_l) * K + ch*32 + col_l;
            lptr[i] = Bs + id2 * 512;
        }
    }

    for (int k0 = 0; k0 < K; k0 += BK) {
        __syncthreads();
        #pragma unroll
        for (int i = 0; i < NS; i++) gld16(gptr[i] + k0, lptr[i]);
        __syncthreads();
        #pragma unroll
        for (int kk = 0; kk < KB32; kk++) {
            bf16x8 af[MT], bf[NTW];
            #pragma unroll
            for (int mt = 0; mt < MT; mt++)
                af[mt] = *(const bf16x8*)(As + ((wrow/16 + mt)*KB32 + kk)*512 + ml*32 + q_*8);
            #pragma unroll
            for (int nt = 0; nt < NTW; nt++)
                bf[nt] = *(const bf16x8*)(Bs + ((wcol/16 + nt)*KB32 + kk)*512 + ml*32 + q_*8);
            #pragma unroll
            for (int mt = 0; mt < MT; mt++)
                #pragma unroll
                for (int nt = 0; nt < NTW; nt++)
                    acc[mt][nt] = __builtin_amdgcn_mfma_f32_16x16x32_bf16(af[mt], bf[nt], acc[mt][nt], 0, 0, 0);
        }
    }

    if (MODE == 0) {
        #pragma unroll
        for (int mt = 0; mt < MT; mt++)
            #pragma unroll
            for (int nt = 0; nt < NTW; nt++) {
                floatx4 v = acc[mt][nt];
                int col = n0 + wcol + nt*16 + ml;
                int which = col >> 10;
                int nn = col & 1023;
                int h = nn >> 6, d = nn & 63;
                if (which < 2) {
                    ushort_t* dst = (which == 0) ? qb : kb;
                    float sc = (which == 0) ? QSCALE : 1.0f;
                    for (int r = 0; r < 4; r++) {
                        int rowg = m0 + wrow + mt*16 + q_*4 + r;
                        int b = rowg >> 11, s = rowg & 2047;
                        dst[(((int64_t)(b*16 + h) * 2048 + s) << 6) + d] = f2bf(v[r] * sc);
                    }
                } else {
                    int rowg0 = m0 + wrow + mt*16 + q_*4;
                    int b = rowg0 >> 11, sbase = rowg0 & 2047;
                    ushort4 o;
                    o.x = f2bf(v[0]); o.y = f2bf(v[1]); o.z = f2bf(v[2]); o.w = f2bf(v[3]);
                    *(ushort4*)(vtb + (((int64_t)(b*16 + h) * 64 + d) << 11) + sbase) = o;
                }
            }
    } else {
        #pragma unroll
        for (int mt = 0; mt < MT; mt++)
            #pragma unroll
            for (int nt = 0; nt < NTW; nt++) {
                floatx4 v = acc[mt][nt];
                int col = n0 + wcol + nt*16 + ml;
                float bv = bias[col];
                for (int r = 0; r < 4; r++) {
                    int rowg = m0 + wrow + mt*16 + q_*4 + r;
                    outf[(int64_t)rowg * N + col] = v[r] + bv;
                }
            }
    }
}

// ---------------- fused masked flash attention: 4 waves x 16 q-rows, 1024 blocks ----
// r8-verified (50.0us): 64 q-rows/block, LDS 50176B -> 3 blocks/CU, 12 waves/CU,
// grid 1024 > 768 slots -> continuous backfill; heavy views dispatched first.
// Swapped QK^T (mfma(K,Q)) so lane holds P[q=ml][k=kt*16+4*q_+r] -> contiguous
// b64 P stores, scalar lsum.
__global__ __launch_bounds__(256, 3)
void attn_kernel(const ushort_t* __restrict__ Q, const ushort_t* __restrict__ Kb,
                 const ushort_t* __restrict__ Vt, ushort_t* __restrict__ Out)
{
    __shared__ ushort_t Kl[8192];        // 16KB: 16 blocks of 1KB (lane-linear)
    __shared__ ushort_t Vl[8192];        // 16KB
    __shared__ ushort_t Pl[4 * 16 * 136];// per-wave P tile [16 q][128 k], stride 136

    int bi = blockIdx.x;                 // 1024 blocks
    int bh = (bi & 7) + 8 * ((bi >> 3) & 3);   // low 3 bits -> XCD spread
    int qt = (bi >> 5) & 3;              // 64-row q piece
    int qv = 7 - (bi >> 7);              // heavy views first (qv=7 at t=0)
    int b = bh >> 4, h = bh & 15;
    int tid = threadIdx.x;
    int wave = tid >> 6, lane = tid & 63;
    int q_ = lane >> 4, ml = lane & 15;
    int rlane = lane & 15, clane = lane >> 4;
    int s0 = qv*256 + qt*64 + wave*16;   // this wave's 16 q-rows

    const ushort_t* Kbh = Kb + ((int64_t)bh << 17);
    const ushort_t* Vbh = Vt + ((int64_t)bh << 17);
    ushort_t* Pw = Pl + wave * (16 * 136);

    const ushort_t* Qp = Q + (((int64_t)bh*2048 + s0 + ml) << 6) + q_*8;
    bf16x8 aq0 = *(const bf16x8*)(Qp);
    bf16x8 aq1 = *(const bf16x8*)(Qp + 32);

    floatx4 o_acc[4];
    for (int i = 0; i < 4; i++) o_acc[i] = floatx4{0.f,0.f,0.f,0.f};
    float lsum = 0.f;                    // partial sum for q-row ml

    const int nviews = (qv < 2) ? 1 : (qv + 1);
    const int vfix = qv ^ 1;             // the single view when nviews==1

    for (int vi = 0; vi < nviews; vi++) {
        int kb0 = ((nviews == 1) ? vfix : vi) * 256;
        for (int ck = 0; ck < 2; ck++) {
            int koff = kb0 + ck * 128;

            __syncthreads();
            #pragma unroll
            for (int i = 0; i < 4; i++) {
                int id = wave*4 + i;
                const ushort_t* gk = Kbh + (((int64_t)(koff + (id >> 1)*16 + rlane)) << 6)
                                         + (id & 1)*32 + clane*8;
                gld16(gk, Kl + id*512);
                const ushort_t* gv = Vbh + ((int64_t)((id & 3)*16 + rlane) << 11)
                                         + koff + (id >> 2)*32 + clane*8;
                gld16(gv, Vl + id*512);
            }
            __syncthreads();

            // ---- S = K @ Q^T : lane -> q-row ml, keys kt*16 + 4*q_ + r ----
            #pragma unroll
            for (int kt = 0; kt < 8; kt++) {
                bf16x8 k0 = *(const bf16x8*)(Kl + kt*1024 + lane*8);
                bf16x8 k1 = *(const bf16x8*)(Kl + kt*1024 + 512 + lane*8);
                floatx4 cz = floatx4{0.f,0.f,0.f,0.f};
                cz = __builtin_amdgcn_mfma_f32_16x16x32_bf16(k0, aq0, cz, 0, 0, 0);
                cz = __builtin_amdgcn_mfma_f32_16x16x32_bf16(k1, aq1, cz, 0, 0, 0);

                float p0 = __builtin_amdgcn_exp2f(cz[0]);
                float p1 = __builtin_amdgcn_exp2f(cz[1]);
                float p2 = __builtin_amdgcn_exp2f(cz[2]);
                float p3 = __builtin_amdgcn_exp2f(cz[3]);
                lsum += (p0 + p1) + (p2 + p3);
                uint32x2 wv;
                wv[0] = (uint32_t)f2bf(p0) | ((uint32_t)f2bf(p1) << 16);
                wv[1] = (uint32_t)f2bf(p2) | ((uint32_t)f2bf(p3) << 16);
                *(uint32x2*)(Pw + ml*136 + kt*16 + q_*4) = wv;       // ds_write_b64
            }

            asm volatile("s_waitcnt lgkmcnt(0)" ::: "memory");  // wave-private P visible

            // ---- O += P @ V ----
            #pragma unroll
            for (int g = 0; g < 4; g++) {
                bf16x8 ap = *(const bf16x8*)(Pw + ml*136 + g*32 + q_*8);
                #pragma unroll
                for (int dt = 0; dt < 4; dt++) {
                    bf16x8 vv = *(const bf16x8*)(Vl + (g*4 + dt)*512 + lane*8);
                    o_acc[dt] = __builtin_amdgcn_mfma_f32_16x16x32_bf16(ap, vv, o_acc[dt], 0, 0, 0);
                }
            }
        }
    }

    // reduce l across the 4 quarters holding the same q-row (lanes ml + 16*q_)
    lsum += __shfl_xor(lsum, 16);
    lsum += __shfl_xor(lsum, 32);
    // o_acc rows are q = q_*4 + r; that row's total l lives at lane (q_*4 + r)
    float rinv[4];
    #pragma unroll
    for (int r = 0; r < 4; r++)
        rinv[r] = 1.0f / __shfl(lsum, q_*4 + r);

    // epilogue: Out[b][s][h*64+d] = o/l (bf16)
    #pragma unroll
    for (int dt = 0; dt < 4; dt++)
        #pragma unroll
        for (int r = 0; r < 4; r++) {
            float v = o_acc[dt][r] * rinv[r];
            int sr = s0 + q_*4 + r;
            Out[((int64_t)b*2048 + sr) * 1024 + h*64 + dt*16 + ml] = f2bf(v);
        }
}

extern "C" void kernel_launch(void* const* d_in, const int* in_sizes, int n_in,
                              void* d_out, int out_size, void* d_ws, size_t ws_size,
                              hipStream_t stream) {
    const float* x  = (const float*)d_in[0];
    const float* Wq = (const float*)d_in[1];
    const float* Wk = (const float*)d_in[2];
    const float* Wv = (const float*)d_in[3];
    const float* Wp = (const float*)d_in[4];
    const float* bp = (const float*)d_in[5];
    float* out = (float*)d_out;

    char* ws = (char*)d_ws;
    ushort_t* xb    = (ushort_t*)(ws);
    ushort_t* Wqkvb = (ushort_t*)(ws + ((size_t)8  << 20));
    ushort_t* Wpb   = (ushort_t*)(ws + ((size_t)14 << 20));
    ushort_t* qb    = (ushort_t*)(ws + ((size_t)16 << 20));
    ushort_t* kbuf  = (ushort_t*)(ws + ((size_t)24 << 20));
    ushort_t* vtb   = (ushort_t*)(ws + ((size_t)40 << 20));
    ushort_t* attno = xb;

    cast_kernel<<<8192, 256, 0, stream>>>(x, Wq, Wk, Wv, Wp, xb, Wqkvb, Wpb);

    // QKV projection: 4096 x 3072 x 1024, 128x128 tile, BK=64 -> grid 32x24 (3/CU)
    gemm_bt<128,128,64,0><<<dim3(32, 24), 256, 0, stream>>>(
        xb, Wqkvb, 4096, 3072, 1024, qb, kbuf, vtb, nullptr, nullptr);

    attn_kernel<<<1024, 256, 0, stream>>>(qb, kbuf, vtb, attno);

    // output projection: 4096 x 1024 x 1024, 128x64 tile, BK=64 -> grid 32x16 (2/CU)
    gemm_bt<128,64,64,1><<<dim3(32, 16), 256, 0, stream>>>(
        attno, Wpb, 4096, 1024, 1024, nullptr, nullptr, nullptr, out, bp);
}